// Round 1
// baseline (505.170 us; speedup 1.0000x reference)
//
#include <hip/hip_runtime.h>
#include <hip/hip_bf16.h>
#include <math.h>

#define NN 8192
#define HD 128
#define NB 2
#define EPSF 1e-6f

typedef __attribute__((ext_vector_type(8))) __bf16 bf16x8;
typedef __attribute__((ext_vector_type(4))) float f32x4;

// ---------------- Kernel 1: norm = rsqrt(sum|adj_row| + eps) -----------------
// One wave per row. 8192 fp32 per row, float4 loads, shuffle reduce.
__global__ __launch_bounds__(256) void k_degree(const float* __restrict__ adj,
                                                float* __restrict__ norm) {
    const int row  = blockIdx.x * 4 + (threadIdx.x >> 6);
    const int lane = threadIdx.x & 63;
    const float4* p = (const float4*)(adj + (size_t)row * NN);
    float s = 0.f;
#pragma unroll
    for (int i = 0; i < 32; ++i) {
        float4 v = p[(size_t)i * 64 + lane];
        s += fabsf(v.x) + fabsf(v.y) + fabsf(v.z) + fabsf(v.w);
    }
#pragma unroll
    for (int off = 32; off > 0; off >>= 1) s += __shfl_down(s, off);
    if (lane == 0) norm[row] = rsqrtf(s + EPSF);
}

// ------- Kernel 2: snT[b][h][n] = bf16( (x@W)[b][n][h] * norm[b][n] ) --------
// Block: 16 rows (n) x all 128 h. x rows staged in LDS; W L1/L2-hot.
__global__ __launch_bounds__(256) void k_support(const float* __restrict__ x,
                                                 const float* __restrict__ W,
                                                 const float* __restrict__ norm,
                                                 __hip_bfloat16* __restrict__ snT) {
    const int b  = blockIdx.x >> 9;          // 512 blocks per batch
    const int n0 = (blockIdx.x & 511) * 16;
    __shared__ float xs[16][132];            // pad 132: float4-aligned, 2-way banks (free)
    const int t = threadIdx.x;
    {
        const int r = t >> 4, c0 = (t & 15) * 8;
        const float* src = x + ((size_t)(b * NN + n0 + r)) * HD + c0;
        *(float4*)&xs[r][c0]     = *(const float4*)src;
        *(float4*)&xs[r][c0 + 4] = *(const float4*)(src + 4);
    }
    __syncthreads();
    const int nl = t & 15;
    const int h0 = (t >> 4) * 8;
    float s[8] = {0.f,0.f,0.f,0.f,0.f,0.f,0.f,0.f};
#pragma unroll 4
    for (int k = 0; k < HD; ++k) {
        const float xv = xs[nl][k];
        const float* wr = W + k * HD + h0;
        float4 wa = *(const float4*)wr;
        float4 wb = *(const float4*)(wr + 4);
        s[0] += xv * wa.x; s[1] += xv * wa.y; s[2] += xv * wa.z; s[3] += xv * wa.w;
        s[4] += xv * wb.x; s[5] += xv * wb.y; s[6] += xv * wb.z; s[7] += xv * wb.w;
    }
    const float nv = norm[b * NN + n0 + nl];
#pragma unroll
    for (int hb = 0; hb < 8; ++hb)
        snT[((size_t)b * HD + h0 + hb) * NN + n0 + nl] = __float2bfloat16(s[hb] * nv);
}

// ---- Kernel 3: out = elu( norm_m * (adj[b] @ snT[b]^T) + bias ) -------------
// BM=64, BK=64, 512 threads = 8 waves (4 row-groups x 2 col-groups of 64 h).
// adj reg-staged fp32 -> bf16 -> XOR-swizzled LDS (conflict-free ds_read_b128).
// B fragments read directly from global snT (L2/L3-resident, 4 MB total).
__global__ __launch_bounds__(512) void k_gemm(const float* __restrict__ adj,
                                              const __hip_bfloat16* __restrict__ snT,
                                              const float* __restrict__ norm,
                                              const float* __restrict__ bias,
                                              float* __restrict__ out) {
    const int b  = blockIdx.y;
    const int m0 = blockIdx.x * 64;
    const float* adjB = adj + (size_t)b * NN * NN;
    const __hip_bfloat16* snB = snT + (size_t)b * HD * NN;

    __shared__ __align__(16) char A_lds[2][64 * 128];  // 2 x (64 rows x 64 bf16)

    const int t    = threadIdx.x;
    const int lane = t & 63;
    const int w    = t >> 6;
    const int wr   = w & 3;       // row group (16 rows each)
    const int wc   = w >> 2;      // col group (64 h each)

    // staging: thread t loads row sr, k-slot sc (8 fp32 = 2 float4)
    const int sr = t >> 3;
    const int sc = t & 7;
    const float* gA = adjB + (size_t)(m0 + sr) * NN + sc * 8;
    const int woff = sr * 128 + ((sc ^ (sr & 7)) * 16);   // XOR-swizzled 16B slot

    // fragment geometry (mfma_f32_16x16x32_bf16)
    const int fr   = lane & 15;   // A row-in-16 / B col-in-16 / D col
    const int g    = lane >> 4;   // k-group (8 elems each) / D row-quad
    const int arow = wr * 16 + fr;

    f32x4 acc[4] = {{0.f,0.f,0.f,0.f},{0.f,0.f,0.f,0.f},
                    {0.f,0.f,0.f,0.f},{0.f,0.f,0.f,0.f}};

    float4 r0 = *(const float4*)gA;
    float4 r1 = *(const float4*)(gA + 4);

    const int NSTEP = NN / 64;
    for (int s = 0; s < NSTEP; ++s) {
        // convert + write current tile to LDS buffer s&1
        bf16x8 pk;
        pk[0] = (__bf16)r0.x; pk[1] = (__bf16)r0.y; pk[2] = (__bf16)r0.z; pk[3] = (__bf16)r0.w;
        pk[4] = (__bf16)r1.x; pk[5] = (__bf16)r1.y; pk[6] = (__bf16)r1.z; pk[7] = (__bf16)r1.w;
        *(bf16x8*)(&A_lds[s & 1][woff]) = pk;
        __syncthreads();   // single barrier/iter is safe with double buffering

        // B fragments for this K-step (issued BEFORE staging loads so their
        // vmcnt waits never drain the prefetch)
        const int k0 = s * 64;
        bf16x8 bfr[2][4];
#pragma unroll
        for (int kk = 0; kk < 2; ++kk)
#pragma unroll
            for (int tt = 0; tt < 4; ++tt) {
                const int brow = wc * 64 + tt * 16 + fr;
                bfr[kk][tt] = *(const bf16x8*)(snB + (size_t)brow * NN + k0 + kk * 32 + g * 8);
            }

        // prefetch next adj tile into regs (HBM latency hidden under MFMAs)
        if (s + 1 < NSTEP) {
            const float* gn = gA + (s + 1) * 64;
            r0 = *(const float4*)gn;
            r1 = *(const float4*)(gn + 4);
        }

        const char* lb = A_lds[s & 1];
#pragma unroll
        for (int kk = 0; kk < 2; ++kk) {
            const int slot = kk * 4 + g;
            bf16x8 af = *(const bf16x8*)(lb + arow * 128 + ((slot ^ (arow & 7)) * 16));
#pragma unroll
            for (int tt = 0; tt < 4; ++tt)
                acc[tt] = __builtin_amdgcn_mfma_f32_16x16x32_bf16(af, bfr[kk][tt], acc[tt], 0, 0, 0);
        }
    }

    // epilogue: * norm_m + bias, elu, store fp32
    const float* normB = norm + b * NN;
    float nv[4];
#pragma unroll
    for (int j = 0; j < 4; ++j) nv[j] = normB[m0 + wr * 16 + g * 4 + j];
#pragma unroll
    for (int tt = 0; tt < 4; ++tt) {
        const int h  = wc * 64 + tt * 16 + fr;
        const float bv = bias[h];
#pragma unroll
        for (int j = 0; j < 4; ++j) {
            const int m = m0 + wr * 16 + g * 4 + j;
            float v = acc[tt][j] * nv[j] + bv;
            out[((size_t)b * NN + m) * HD + h] = v > 0.f ? v : expm1f(v);
        }
    }
}

extern "C" void kernel_launch(void* const* d_in, const int* in_sizes, int n_in,
                              void* d_out, int out_size, void* d_ws, size_t ws_size,
                              hipStream_t stream) {
    const float* x    = (const float*)d_in[0];
    const float* adj  = (const float*)d_in[1];
    const float* W    = (const float*)d_in[2];
    const float* bias = (const float*)d_in[3];
    float* out = (float*)d_out;

    float* norm = (float*)d_ws;                                    // 16384 f32 (64 KB)
    __hip_bfloat16* snT = (__hip_bfloat16*)((char*)d_ws + 65536);  // 2x128x8192 bf16 (4 MB)

    k_degree <<<dim3(NB * NN / 4),  dim3(256), 0, stream>>>(adj, norm);
    k_support<<<dim3(NB * NN / 16), dim3(256), 0, stream>>>(x, W, norm, snT);
    k_gemm   <<<dim3(NN / 64, NB),  dim3(512), 0, stream>>>(adj, snT, norm, bias, out);
}

// Round 2
// 338.363 us; speedup vs baseline: 1.4930x; 1.4930x over previous
//
#include <hip/hip_runtime.h>
#include <hip/hip_bf16.h>
#include <math.h>

#define NN 8192
#define HD 128
#define NB 2
#define EPSF 1e-6f
#define KSPLIT 4
#define KCHUNK (NN / KSPLIT)   // 2048
#define NIT (KCHUNK / 32)      // 64 K-steps of 32 per wave

typedef __attribute__((ext_vector_type(8))) __bf16 bf16x8;
typedef __attribute__((ext_vector_type(4))) float f32x4;

// ---------------- Kernel 1: norm = rsqrt(sum|adj_row| + eps) -----------------
__global__ __launch_bounds__(256) void k_degree(const float* __restrict__ adj,
                                                float* __restrict__ norm) {
    const int row  = blockIdx.x * 4 + (threadIdx.x >> 6);
    const int lane = threadIdx.x & 63;
    const float4* p = (const float4*)(adj + (size_t)row * NN);
    float s = 0.f;
#pragma unroll
    for (int i = 0; i < 32; ++i) {
        float4 v = p[(size_t)i * 64 + lane];
        s += fabsf(v.x) + fabsf(v.y) + fabsf(v.z) + fabsf(v.w);
    }
#pragma unroll
    for (int off = 32; off > 0; off >>= 1) s += __shfl_down(s, off);
    if (lane == 0) norm[row] = rsqrtf(s + EPSF);
}

// ------- Kernel 2: snT[b][h][n] = bf16( (x@W)[b][n][h] * norm[b][n] ) --------
__global__ __launch_bounds__(256) void k_support(const float* __restrict__ x,
                                                 const float* __restrict__ W,
                                                 const float* __restrict__ norm,
                                                 __hip_bfloat16* __restrict__ snT) {
    const int b  = blockIdx.x >> 9;
    const int n0 = (blockIdx.x & 511) * 16;
    __shared__ float xs[16][132];
    const int t = threadIdx.x;
    {
        const int r = t >> 4, c0 = (t & 15) * 8;
        const float* src = x + ((size_t)(b * NN + n0 + r)) * HD + c0;
        *(float4*)&xs[r][c0]     = *(const float4*)src;
        *(float4*)&xs[r][c0 + 4] = *(const float4*)(src + 4);
    }
    __syncthreads();
    const int nl = t & 15;
    const int h0 = (t >> 4) * 8;
    float s[8] = {0.f,0.f,0.f,0.f,0.f,0.f,0.f,0.f};
#pragma unroll 4
    for (int k = 0; k < HD; ++k) {
        const float xv = xs[nl][k];
        const float* wr = W + k * HD + h0;
        float4 wa = *(const float4*)wr;
        float4 wb = *(const float4*)(wr + 4);
        s[0] += xv * wa.x; s[1] += xv * wa.y; s[2] += xv * wa.z; s[3] += xv * wa.w;
        s[4] += xv * wb.x; s[5] += xv * wb.y; s[6] += xv * wb.z; s[7] += xv * wb.w;
    }
    const float nv = norm[b * NN + n0 + nl];
#pragma unroll
    for (int hb = 0; hb < 8; ++hb)
        snT[((size_t)b * HD + h0 + hb) * NN + n0 + nl] = __float2bfloat16(s[hb] * nv);
}

__device__ inline bf16x8 cvt8(float4 a, float4 b) {
    bf16x8 r;
    r[0] = (__bf16)a.x; r[1] = (__bf16)a.y; r[2] = (__bf16)a.z; r[3] = (__bf16)a.w;
    r[4] = (__bf16)b.x; r[5] = (__bf16)b.y; r[6] = (__bf16)b.z; r[7] = (__bf16)b.w;
    return r;
}

// ---- Kernel 3: out = elu( norm_m * (adj[b] @ snT[b]^T) + bias ) -------------
// Barrier-free K-loop: each wave independently streams adj (HBM) straight into
// A-fragments (fp32->bf16 in regs) and snT (L2) into B-fragments, both depth-1
// software-pipelined via ping-pong register banks. Block = one 32-row strip,
// 4 waves = 4 disjoint K-quarters; LDS reduction + fused epilogue at the end.
__global__ __launch_bounds__(256, 2) void k_gemm2(const float* __restrict__ adj,
                                                  const __hip_bfloat16* __restrict__ snT,
                                                  const float* __restrict__ norm,
                                                  const float* __restrict__ bias,
                                                  float* __restrict__ out) {
    const int b    = blockIdx.y;
    const int m0   = blockIdx.x * 32;
    const int w    = threadIdx.x >> 6;     // wave = K-quarter owner
    const int lane = threadIdx.x & 63;
    const int fr   = lane & 15;
    const int g    = lane >> 4;

    const float* adjB = adj + (size_t)b * NN * NN;
    const __hip_bfloat16* snB = snT + (size_t)b * HD * NN;
    const int kbase = w * KCHUNK;

    const float* a0p = adjB + (size_t)(m0 + fr) * NN + kbase + g * 8;   // m-tile 0
    const float* a1p = a0p + (size_t)16 * NN;                           // m-tile 1
    const __hip_bfloat16* bp = snB + (size_t)fr * NN + kbase + g * 8;

    f32x4 acc[2][8] = {};

    float4 Aa0[2], Ab0[2], Aa1[2], Ab1[2];   // [mi], banks 0/1
    bf16x8 B0[8], B1[8];

#define PREFETCH(AaX, AbX, BX, it) do {                                   \
        const int ko_ = (it) * 32;                                        \
        AaX[0] = *(const float4*)(a0p + ko_);                             \
        AbX[0] = *(const float4*)(a0p + ko_ + 4);                         \
        AaX[1] = *(const float4*)(a1p + ko_);                             \
        AbX[1] = *(const float4*)(a1p + ko_ + 4);                         \
        _Pragma("unroll")                                                 \
        for (int tt = 0; tt < 8; ++tt)                                    \
            BX[tt] = *(const bf16x8*)(bp + tt * 16 * NN + ko_);           \
    } while (0)

#define COMPUTE(AaX, AbX, BX) do {                                        \
        bf16x8 af0_ = cvt8(AaX[0], AbX[0]);                               \
        bf16x8 af1_ = cvt8(AaX[1], AbX[1]);                               \
        _Pragma("unroll")                                                 \
        for (int tt = 0; tt < 8; ++tt) {                                  \
            acc[0][tt] = __builtin_amdgcn_mfma_f32_16x16x32_bf16(af0_, BX[tt], acc[0][tt], 0, 0, 0); \
            acc[1][tt] = __builtin_amdgcn_mfma_f32_16x16x32_bf16(af1_, BX[tt], acc[1][tt], 0, 0, 0); \
        }                                                                 \
    } while (0)

    PREFETCH(Aa0, Ab0, B0, 0);
#pragma unroll 1
    for (int i = 0; i < NIT - 2; i += 2) {
        PREFETCH(Aa1, Ab1, B1, i + 1);
        COMPUTE(Aa0, Ab0, B0);
        PREFETCH(Aa0, Ab0, B0, i + 2);
        COMPUTE(Aa1, Ab1, B1);
    }
    PREFETCH(Aa1, Ab1, B1, NIT - 1);
    COMPUTE(Aa0, Ab0, B0);
    COMPUTE(Aa1, Ab1, B1);
#undef PREFETCH
#undef COMPUTE

    // ---- cross-wave (K-split) reduction through LDS ----
    __shared__ float red[32][132];   // stride 132: g*4-row writes conflict-free
    for (int wv = 0; wv < KSPLIT; ++wv) {
        if (w == wv) {
#pragma unroll
            for (int mi = 0; mi < 2; ++mi)
#pragma unroll
                for (int tt = 0; tt < 8; ++tt)
#pragma unroll
                    for (int j = 0; j < 4; ++j) {
                        const int r = mi * 16 + g * 4 + j;
                        const int c = tt * 16 + fr;
                        if (wv == 0) red[r][c] = acc[mi][tt][j];
                        else         red[r][c] += acc[mi][tt][j];
                    }
        }
        __syncthreads();
    }

    // ---- fused epilogue: *norm_m + bias, elu, coalesced float4 stores ----
    const int t = threadIdx.x;
    float* otile = out + ((size_t)b * NN + m0) * HD;   // 32x128 contiguous
    const float* normB = norm + b * NN + m0;
#pragma unroll
    for (int rep = 0; rep < 4; ++rep) {
        const int flat = rep * 1024 + t * 4;
        const int r = flat >> 7;          // row in strip
        const int c = flat & 127;         // h
        const float nm = normB[r];
        float4 v = *(const float4*)&red[r][c];
        float4 bv = *(const float4*)&bias[c];
        float4 o;
        o.x = v.x * nm + bv.x; o.y = v.y * nm + bv.y;
        o.z = v.z * nm + bv.z; o.w = v.w * nm + bv.w;
        o.x = o.x > 0.f ? o.x : expm1f(o.x);
        o.y = o.y > 0.f ? o.y : expm1f(o.y);
        o.z = o.z > 0.f ? o.z : expm1f(o.z);
        o.w = o.w > 0.f ? o.w : expm1f(o.w);
        *(float4*)&otile[flat] = o;
    }
}

extern "C" void kernel_launch(void* const* d_in, const int* in_sizes, int n_in,
                              void* d_out, int out_size, void* d_ws, size_t ws_size,
                              hipStream_t stream) {
    const float* x    = (const float*)d_in[0];
    const float* adj  = (const float*)d_in[1];
    const float* W    = (const float*)d_in[2];
    const float* bias = (const float*)d_in[3];
    float* out = (float*)d_out;

    float* norm = (float*)d_ws;                                    // 16384 f32
    __hip_bfloat16* snT = (__hip_bfloat16*)((char*)d_ws + 65536);  // 2x128x8192 bf16 (4 MB)

    k_degree <<<dim3(NB * NN / 4),  dim3(256), 0, stream>>>(adj, norm);
    k_support<<<dim3(NB * NN / 16), dim3(256), 0, stream>>>(x, W, norm, snT);
    k_gemm2  <<<dim3(NN / 32, NB),  dim3(256), 0, stream>>>(adj, snT, norm, bias, out);
}